// Round 1
// baseline (1112.316 us; speedup 1.0000x reference)
//
#include <hip/hip_runtime.h>
#include <stdint.h>

typedef float  f32x4 __attribute__((ext_vector_type(4)));
typedef short  s16x8 __attribute__((ext_vector_type(8)));
typedef unsigned short u16x4 __attribute__((ext_vector_type(4)));

#define DEV __device__ __forceinline__

DEV unsigned short f2bf(float f) {
  union { float f; unsigned int u; } v; v.f = f;
  unsigned int u = v.u;
  return (unsigned short)((u + 0x7fffu + ((u >> 16) & 1u)) >> 16);
}
DEV float bf2f(unsigned short h) {
  union { unsigned int u; float f; } v; v.u = ((unsigned int)h) << 16;
  return v.f;
}

static constexpr int SUBW = 40;   // 32 data shorts + 8 pad (bank-conflict spread)

// Stage a 128x32 tile into LDS as bf16; MODE 0 = fp32 source (convert, hi[/lo]),
// MODE 1 = bf16 source (direct copy). TRIPLE adds the lo sub-tile at +SUBW.
template<int MODE, bool TRIPLE, int ROWW>
DEV void stage_tile(const void* __restrict__ P, long rowBase, int lda, int k0,
                    int srow, int scg, unsigned short* __restrict__ lds)
{
  unsigned short* dst = lds + srow * ROWW + scg;
  if (MODE == 0) {
    const float* A = (const float*)P + rowBase + (long)srow * lda + k0 + scg;
    unsigned short hi[16];
    unsigned short lo[16];
    #pragma unroll
    for (int v = 0; v < 4; ++v) {
      f32x4 x = *(const f32x4*)(A + 4 * v);
      #pragma unroll
      for (int e = 0; e < 4; ++e) {
        float f = x[e];
        unsigned short h = f2bf(f);
        hi[v * 4 + e] = h;
        if (TRIPLE) lo[v * 4 + e] = f2bf(f - bf2f(h));
      }
    }
    *(s16x8*)(dst + 0) = *(const s16x8*)&hi[0];
    *(s16x8*)(dst + 8) = *(const s16x8*)&hi[8];
    if (TRIPLE) {
      *(s16x8*)(dst + SUBW + 0) = *(const s16x8*)&lo[0];
      *(s16x8*)(dst + SUBW + 8) = *(const s16x8*)&lo[8];
    }
  } else {
    const unsigned short* A = (const unsigned short*)P + rowBase + (long)srow * lda + k0 + scg;
    *(s16x8*)(dst + 0) = *(const s16x8*)(A + 0);
    *(s16x8*)(dst + 8) = *(const s16x8*)(A + 8);
  }
}

// C[m,n] = sum_k A[m,k]*B[n,k] (+bias[n])   (NT, both operands K-contiguous)
// AM/BMD: 0 = fp32 source (convert on the fly), 1 = bf16 source
// TRIPLE: hi/lo 3-pass (Ah*Bh + Ah*Bl + Al*Bh) for ~fp32-grade product
// OM: 0 = fp32 row-major (+bias); 1 = bf16 scatter to vT[((b*8+h)*256+i)*256+s] (+bias);
//     2 = bf16 row-major (+batch C offset when BATCHED)
// BATCHED: blockIdx.z batches of 256x256x256 (A,B stride 65536; C = agg layout)
template<int AM, int BMD, bool TRIPLE, int OM, bool BATCHED>
__global__ __launch_bounds__(256)
void gemm_nt(const void* __restrict__ Ap, const void* __restrict__ Bp,
             const float* __restrict__ bias, void* __restrict__ Cp,
             int M, int N, int K, int lda, int ldb, int ldc)
{
  constexpr int ROWW = (TRIPLE ? 2 : 1) * SUBW;
  __shared__ unsigned short lA[128 * ROWW];
  __shared__ unsigned short lB[128 * ROWW];

  const int tid  = threadIdx.x;
  const int lane = tid & 63;
  const int wid  = tid >> 6;
  const int wr   = wid >> 1;   // wave row (0..1) -> 64-row half
  const int wc   = wid & 1;    // wave col (0..1) -> 64-col half

  const int z  = blockIdx.z;
  const int m0 = blockIdx.y * 128;
  const int n0 = blockIdx.x * 128;

  long aBase = (long)m0 * lda;
  long bBase = (long)n0 * ldb;
  if (BATCHED) {
    aBase += (long)z * 256 * 256;
    bBase += (long)z * 256 * 256;
  }

  const int srow = tid >> 1;        // 0..127: tile row staged by this thread
  const int scg  = (tid & 1) * 16;  // 0 or 16: k-subrange

  f32x4 acc[4][4];
  #pragma unroll
  for (int i = 0; i < 4; ++i)
    #pragma unroll
    for (int j = 0; j < 4; ++j)
      acc[i][j] = (f32x4)(0.0f);

  const int fr   = lane & 15;        // fragment row/col
  const int krow = (lane >> 4) * 8;  // k-offset within 32-wide subtile

  for (int kt = 0; kt < K; kt += 32) {
    stage_tile<AM,  TRIPLE, ROWW>(Ap, aBase, lda, kt, srow, scg, lA);
    stage_tile<BMD, TRIPLE, ROWW>(Bp, bBase, ldb, kt, srow, scg, lB);
    __syncthreads();

    s16x8 a0[4], b0[4];
    #pragma unroll
    for (int i = 0; i < 4; ++i)
      a0[i] = *(const s16x8*)&lA[(wr * 64 + i * 16 + fr) * ROWW + krow];
    #pragma unroll
    for (int j = 0; j < 4; ++j)
      b0[j] = *(const s16x8*)&lB[(wc * 64 + j * 16 + fr) * ROWW + krow];

    #pragma unroll
    for (int i = 0; i < 4; ++i)
      #pragma unroll
      for (int j = 0; j < 4; ++j)
        acc[i][j] = __builtin_amdgcn_mfma_f32_16x16x32_bf16(a0[i], b0[j], acc[i][j], 0, 0, 0);

    if (TRIPLE) {
      s16x8 t[4];
      #pragma unroll
      for (int j = 0; j < 4; ++j)   // B-lo
        t[j] = *(const s16x8*)&lB[(wc * 64 + j * 16 + fr) * ROWW + SUBW + krow];
      #pragma unroll
      for (int i = 0; i < 4; ++i)
        #pragma unroll
        for (int j = 0; j < 4; ++j)
          acc[i][j] = __builtin_amdgcn_mfma_f32_16x16x32_bf16(a0[i], t[j], acc[i][j], 0, 0, 0);
      #pragma unroll
      for (int i = 0; i < 4; ++i)   // A-lo
        t[i] = *(const s16x8*)&lA[(wr * 64 + i * 16 + fr) * ROWW + SUBW + krow];
      #pragma unroll
      for (int i = 0; i < 4; ++i)
        #pragma unroll
        for (int j = 0; j < 4; ++j)
          acc[i][j] = __builtin_amdgcn_mfma_f32_16x16x32_bf16(t[i], b0[j], acc[i][j], 0, 0, 0);
    }
    __syncthreads();
  }

  // Epilogue. C/D fragment: col = lane&15, row = (lane>>4)*4 + reg  [m89-verified]
  const int rg = (lane >> 4) * 4;
  #pragma unroll
  for (int j = 0; j < 4; ++j) {
    const int gn = n0 + wc * 64 + j * 16 + fr;
    const float bvl = bias ? bias[gn] : 0.0f;
    #pragma unroll
    for (int i = 0; i < 4; ++i) {
      const int gmB = m0 + wr * 64 + i * 16 + rg;
      f32x4 v = acc[i][j];
      #pragma unroll
      for (int r = 0; r < 4; ++r) {
        const int gm = gmB + r;
        const float val = v[r] + bvl;
        if (OM == 0) {
          ((float*)Cp)[(long)gm * ldc + gn] = val;
        } else if (OM == 2) {
          long cb = 0;
          if (BATCHED) cb = (long)(z >> 3) * 256 * ldc + (long)(z & 7) * 256;
          ((unsigned short*)Cp)[cb + (long)gm * ldc + gn] = f2bf(val);
        } else { // OM == 1: vT[((b*8+h)*256 + i)*256 + s] = v_proj[b*256+s, h*256+i]
          const int b = gm >> 8, s = gm & 255, h = gn >> 8, ii = gn & 255;
          ((unsigned short*)Cp)[((long)((b * 8 + h) * 256 + ii) << 8) + s] = f2bf(val);
        }
      }
    }
  }
}

// Circular correlation + softmax, one wave per (b,h,l) row.
// corr[d] = sum_t q[t]*k[(t-d) mod 256] = sum_u q[(u+d) mod 256]*k[u]
// lane holds 4 consecutive lags d = 4*lane .. 4*lane+3.
__global__ __launch_bounds__(256)
void corr_softmax(const float* __restrict__ qp, const float* __restrict__ kp,
                  const float* __restrict__ temp, unsigned short* __restrict__ w)
{
  __shared__ float qs[4][520];   // q duplicated [0..511] for mod-free indexing
  __shared__ float ks[4][264];
  const int tid  = threadIdx.x;
  const int lane = tid & 63;
  const int wid  = tid >> 6;
  const int row  = blockIdx.x * 4 + wid;       // 0..65535 = ((b*8+h)*256+l)
  const int b = row >> 11;
  const int h = (row >> 8) & 7;
  const int l = row & 255;
  const long base = (long)(b * 256 + l) * 2048 + h * 256;

  {
    f32x4 qv = *(const f32x4*)(qp + base + 4 * lane);
    f32x4 kv = *(const f32x4*)(kp + base + 4 * lane);
    *(f32x4*)&qs[wid][4 * lane]       = qv;
    *(f32x4*)&qs[wid][256 + 4 * lane] = qv;
    *(f32x4*)&ks[wid][4 * lane]       = kv;
  }
  __syncthreads();

  float c0 = 0.f, c1 = 0.f, c2 = 0.f, c3 = 0.f;
  const int d = 4 * lane;
  const float* Q  = &qs[wid][0];
  const float* Kv = &ks[wid][0];
  #pragma unroll 4
  for (int u0 = 0; u0 < 256; u0 += 4) {
    f32x4 K4 = *(const f32x4*)(Kv + u0);          // uniform (broadcast)
    f32x4 Qa = *(const f32x4*)(Q + u0 + d);       // aligned: u0%4==0, d%4==0
    f32x4 Qb = *(const f32x4*)(Q + u0 + d + 4);
    c0 += K4[0]*Qa[0] + K4[1]*Qa[1] + K4[2]*Qa[2] + K4[3]*Qa[3];
    c1 += K4[0]*Qa[1] + K4[1]*Qa[2] + K4[2]*Qa[3] + K4[3]*Qb[0];
    c2 += K4[0]*Qa[2] + K4[1]*Qa[3] + K4[2]*Qb[0] + K4[3]*Qb[1];
    c3 += K4[0]*Qa[3] + K4[1]*Qb[0] + K4[2]*Qb[1] + K4[3]*Qb[2];
  }

  const float invT = 1.0f / temp[h];
  float mx = fmaxf(fmaxf(c0, c1), fmaxf(c2, c3));
  #pragma unroll
  for (int off = 32; off >= 1; off >>= 1) mx = fmaxf(mx, __shfl_xor(mx, off, 64));
  const float e0 = __expf((c0 - mx) * invT);
  const float e1 = __expf((c1 - mx) * invT);
  const float e2 = __expf((c2 - mx) * invT);
  const float e3 = __expf((c3 - mx) * invT);
  float sm = e0 + e1 + e2 + e3;
  #pragma unroll
  for (int off = 32; off >= 1; off >>= 1) sm += __shfl_xor(sm, off, 64);
  const float rs = 1.0f / sm;
  u16x4 o;
  o[0] = f2bf(e0 * rs); o[1] = f2bf(e1 * rs); o[2] = f2bf(e2 * rs); o[3] = f2bf(e3 * rs);
  *(u16x4*)(w + (long)row * 256 + d) = o;
}

extern "C" void kernel_launch(void* const* d_in, const int* in_sizes, int n_in,
                              void* d_out, int out_size, void* d_ws, size_t ws_size,
                              hipStream_t stream) {
  (void)in_sizes; (void)n_in; (void)out_size; (void)ws_size;
  const float* queries = (const float*)d_in[0];
  const float* keys    = (const float*)d_in[1];
  const float* values  = (const float*)d_in[2];
  const float* Wq = (const float*)d_in[3];
  const float* bq = (const float*)d_in[4];
  const float* Wk = (const float*)d_in[5];
  const float* bk = (const float*)d_in[6];
  const float* Wv = (const float*)d_in[7];
  const float* bv = (const float*)d_in[8];
  const float* Wo = (const float*)d_in[9];
  const float* bo = (const float*)d_in[10];
  const float* temp = (const float*)d_in[11];

  // workspace layout (peak 192 MiB):
  //   [0,64M)    qproj fp32 [8192][2048]   -> later overlaid by out2 (bf16, 32M)
  //   [64M,128M) kproj fp32 [8192][2048]
  //   [128M,160M) wgt  bf16 [(b*8+h)*256+l][256]
  //   [160M,192M) vT   bf16 [(b*8+h)*256+i][256]  (s-contiguous)
  char* ws = (char*)d_ws;
  float* qproj          = (float*)(ws);
  float* kproj          = (float*)(ws + (64ull << 20));
  unsigned short* wgt   = (unsigned short*)(ws + (128ull << 20));
  unsigned short* vT    = (unsigned short*)(ws + (160ull << 20));
  unsigned short* out2  = (unsigned short*)(ws);   // overlays dead qproj

  dim3 blk(256);
  dim3 gBig(16, 64, 1);

  // Q,K projections: triple-precision bf16 MFMA (softmax-sensitive)
  gemm_nt<0,0,true,0,false><<<gBig, blk, 0, stream>>>(queries, Wq, bq, qproj,
                                                      8192, 2048, 2048, 2048, 2048, 2048);
  gemm_nt<0,0,true,0,false><<<gBig, blk, 0, stream>>>(keys, Wk, bk, kproj,
                                                      8192, 2048, 2048, 2048, 2048, 2048);
  // V projection: plain bf16, epilogue scatters transposed vT[b,h,i,s]
  gemm_nt<0,0,false,1,false><<<gBig, blk, 0, stream>>>(values, Wv, bv, vT,
                                                       8192, 2048, 2048, 2048, 2048, 0);
  // circular correlation + softmax -> bf16 weights
  corr_softmax<<<dim3(16384), blk, 0, stream>>>(qproj, kproj, temp, wgt);
  // aggregation: out2[b*256+l][h*256+i] = sum_s wgt[bhl][s] * vT[bhi][s]
  gemm_nt<1,1,false,2,true><<<dim3(2, 2, 256), blk, 0, stream>>>(wgt, vT, nullptr, out2,
                                                                 256, 256, 256, 256, 256, 2048);
  // O projection -> d_out (fp32)
  gemm_nt<1,0,false,0,false><<<gBig, blk, 0, stream>>>(out2, Wo, bo, (float*)d_out,
                                                       8192, 2048, 2048, 2048, 2048, 2048);
}